// Round 4
// baseline (576.940 us; speedup 1.0000x reference)
//
#include <hip/hip_runtime.h>

// Problem constants (from reference): B=16, F=257, M=6, T=1000, N_ITER=2
#define BQ 16
#define FQ 257
#define MQ 6
#define TQ 1000
#define T4Q 250                  // TQ/4 float4 columns per row (4000B rows, 16B aligned)
#define BFQ (BQ * FQ)            // 4112 independent (b,f) problems
#define FMTQ (FQ * MQ * TQ)      // 1,542,000  (divisor for per-batch scale mean)

__device__ __forceinline__ float wave_sum(float v) {
    v += __shfl_xor(v, 1);  v += __shfl_xor(v, 2);  v += __shfl_xor(v, 4);
    v += __shfl_xor(v, 8);  v += __shfl_xor(v, 16); v += __shfl_xor(v, 32);
    return v;
}

// compile-time float4 component select (folds under #pragma unroll)
__device__ __forceinline__ float f4c(const float4 v, int e) {
    return e == 0 ? v.x : e == 1 ? v.y : e == 2 ? v.z : v.w;
}

// ---------------------------------------------------------------------------
// K1 (k_stats): per (b,f):
//   V[k][m][n] = (1/T) sum_t r[k,t] * x[m,t] * conj(x[n,t])  + eps on diagonal
//   C[m][n]    =        sum_t x[m,t] * conj(x[n,t])
// 4 waves per (b,f); 21 Hermitian (m<=n) pairs partitioned at COMPILE TIME.
// Reduction/epilogue = R2's verified butterfly + lane-0 store.
// R4: explicit 2-deep software pipeline over the 4 t-chunks (A/B float4
// buffers). R2/R3 evidence: VALUBusy 25-28%, HBM 13% -> waves serialize
// ~900cy HBM latency per chunk with no prefetch (compiler left 400+ VGPRs
// unused at VGPR=88). Pipelining trades ~130 extra VGPRs for load/compute
// overlap.
// Pair partition (21 Hermitian pairs, verified R2 — DO NOT EDIT):
//   W0: (0,0)(0,1)(0,2)(1,1)(1,2)(2,2)   rows {0,1,2}
//   W1: (3,3)(3,4)(3,5)(4,4)(4,5)(5,5)   rows {3,4,5}
//   W2: (0,3)(0,4)(0,5)(1,3)(1,4)        cross part 1
//   W3: (1,5)(2,3)(2,4)(2,5)             cross part 2
// ---------------------------------------------------------------------------
template<int W> struct PL;
template<> struct PL<0> { static constexpr int np = 6;
    static constexpr int pm[6] = {0,0,0,1,1,2};
    static constexpr int pn[6] = {0,1,2,1,2,2}; };
template<> struct PL<1> { static constexpr int np = 6;
    static constexpr int pm[6] = {3,3,3,4,4,5};
    static constexpr int pn[6] = {3,4,5,4,5,5}; };
template<> struct PL<2> { static constexpr int np = 5;
    static constexpr int pm[6] = {0,0,0,1,1,0};
    static constexpr int pn[6] = {3,4,5,3,4,0}; };
template<> struct PL<3> { static constexpr int np = 4;
    static constexpr int pm[6] = {1,2,2,2,0,0};
    static constexpr int pn[6] = {5,3,4,5,0,0}; };

template<int W> __device__ constexpr unsigned rowMaskFn() {
    unsigned msk = 0;
    for (int p = 0; p < PL<W>::np; p++) {
        msk |= 1u << PL<W>::pm[p];
        msk |= 1u << PL<W>::pn[p];
    }
    return msk;
}

template<int W>
__device__ __forceinline__ void stats_work(
    int bf, int lane, const float* __restrict__ rp,
    const float* __restrict__ xrp, const float* __restrict__ xip,
    float* __restrict__ V, float* __restrict__ Cw)
{
    constexpr int NP = PL<W>::np;
    constexpr unsigned rowmask = rowMaskFn<W>();

    float Vre[NP][6], Vim[NP][6], Cre[NP], Cim[NP];
#pragma unroll
    for (int p = 0; p < NP; p++) {
        Cre[p] = 0.0f; Cim[p] = 0.0f;
#pragma unroll
        for (int k = 0; k < 6; k++) { Vre[p][k] = 0.0f; Vim[p][k] = 0.0f; }
    }

    const float4* rp4  = reinterpret_cast<const float4*>(rp);
    const float4* xrp4 = reinterpret_cast<const float4*>(xrp);
    const float4* xip4 = reinterpret_cast<const float4*>(xip);

    float4 Ar[6], Axr[6], Axi[6];     // pipeline buffer A
    float4 Br[6], Bxr[6], Bxi[6];     // pipeline buffer B

    auto load = [&](float4* R, float4* XR, float4* XI, int i) {
#pragma unroll
        for (int k = 0; k < 6; k++) R[k] = rp4[k * T4Q + i];
#pragma unroll
        for (int row = 0; row < 6; row++) {
            if (rowmask & (1u << row)) {           // compile-time folded
                XR[row] = xrp4[row * T4Q + i];
                XI[row] = xip4[row * T4Q + i];
            }
        }
    };

    auto compute = [&](const float4* R, const float4* XR, const float4* XI) {
#pragma unroll
        for (int e = 0; e < 4; e++) {
#pragma unroll
            for (int p = 0; p < NP; p++) {
                const int m = PL<W>::pm[p], n = PL<W>::pn[p];
                if (m == n) {
                    const float arm = f4c(XR[m], e), aim = f4c(XI[m], e);
                    const float pr = arm * arm + aim * aim;
                    Cre[p] += pr;
#pragma unroll
                    for (int k = 0; k < 6; k++) Vre[p][k] += f4c(R[k], e) * pr;
                } else {
                    const float arm = f4c(XR[m], e), aim = f4c(XI[m], e);
                    const float arn = f4c(XR[n], e), ain = f4c(XI[n], e);
                    const float pr = arm * arn + aim * ain;
                    const float pi = aim * arn - arm * ain;
                    Cre[p] += pr;  Cim[p] += pi;
#pragma unroll
                    for (int k = 0; k < 6; k++) {
                        const float rk = f4c(R[k], e);
                        Vre[p][k] += rk * pr;
                        Vim[p][k] += rk * pi;
                    }
                }
            }
        }
    };

    // 2-deep software pipeline over chunks {lane, lane+64, lane+128, lane+192}
    const bool tail = lane < (T4Q - 192);          // lanes 0..57
    load(Ar, Axr, Axi, lane);
    load(Br, Bxr, Bxi, lane + 64);
    compute(Ar, Axr, Axi);
    load(Ar, Axr, Axi, lane + 128);
    compute(Br, Bxr, Bxi);
    if (tail) load(Br, Bxr, Bxi, lane + 192);
    compute(Ar, Axr, Axi);
    if (tail) compute(Br, Bxr, Bxi);

    // butterfly-reduce this wave's accumulators (R2 verified)
#pragma unroll
    for (int p = 0; p < NP; p++) {
        const int m = PL<W>::pm[p], n = PL<W>::pn[p];
        Cre[p] = wave_sum(Cre[p]);
        if (m != n) Cim[p] = wave_sum(Cim[p]);
#pragma unroll
        for (int k = 0; k < 6; k++) {
            Vre[p][k] = wave_sum(Vre[p][k]);
            if (m != n) Vim[p][k] = wave_sum(Vim[p][k]);
        }
    }

    if (lane == 0) {
        const float invT = 1.0f / (float)TQ;
        float2* Vg = reinterpret_cast<float2*>(V + (size_t)bf * 432);
        float2* Cg = reinterpret_cast<float2*>(Cw + (size_t)bf * 72);
#pragma unroll
        for (int p = 0; p < NP; p++) {
            const int m = PL<W>::pm[p], n = PL<W>::pn[p];
            if (m == n) {
#pragma unroll
                for (int k = 0; k < 6; k++)
                    Vg[k * 36 + m * 6 + m] = make_float2(Vre[p][k] * invT + 1e-6f, 0.0f);
                Cg[m * 6 + m] = make_float2(Cre[p], 0.0f);
            } else {
#pragma unroll
                for (int k = 0; k < 6; k++) {
                    const float re = Vre[p][k] * invT, im = Vim[p][k] * invT;
                    Vg[k * 36 + m * 6 + n] = make_float2(re,  im);
                    Vg[k * 36 + n * 6 + m] = make_float2(re, -im);
                }
                Cg[m * 6 + n] = make_float2(Cre[p],  Cim[p]);
                Cg[n * 6 + m] = make_float2(Cre[p], -Cim[p]);
            }
        }
    }
}

__global__ __launch_bounds__(256) void k_stats(
    const float* __restrict__ r, const float* __restrict__ xre,
    const float* __restrict__ xim, float* __restrict__ V,
    float* __restrict__ Cw, float* __restrict__ S)
{
    const int bf   = blockIdx.x;
    const int w    = threadIdx.x >> 6;
    const int lane = threadIdx.x & 63;
    // fused k_zero: S1[16]|S2[16] contiguous; done before any k_iter atomics
    // (stream order guarantees visibility).
    if (bf == 0 && threadIdx.x < 32) S[threadIdx.x] = 0.0f;
    const float* rp  = r   + (size_t)bf * MQ * TQ;
    const float* xrp = xre + (size_t)bf * MQ * TQ;
    const float* xip = xim + (size_t)bf * MQ * TQ;
    switch (w) {
        case 0:  stats_work<0>(bf, lane, rp, xrp, xip, V, Cw); break;
        case 1:  stats_work<1>(bf, lane, rp, xrp, xip, V, Cw); break;
        case 2:  stats_work<2>(bf, lane, rp, xrp, xip, V, Cw); break;
        default: stats_work<3>(bf, lane, rp, xrp, xip, V, Cw); break;
    }
}

// ---------------------------------------------------------------------------
// K2: one ISS iteration (6 sequential k-steps) + trace(Q C Q^H) partial for
// the per-batch scale. 8 lanes per (b,f): lane kp<6 owns row kp of Q and
// V[kp]; pivot row q broadcast via width-8 shuffles.
// R4: register-pressure fix (was ~300 peak VGPR -> scratch spills):
//  - V unpacked directly from float4 loads (no vb[18] staging array)
//  - C load + trace moved AFTER the pivot loop, consumed row-by-row
//    (Cr/Ci[72] never materialized). Peak live ~120 VGPR.
// ---------------------------------------------------------------------------
__global__ __launch_bounds__(256) void k_iter(
    const float* __restrict__ V, const float* __restrict__ Cw,
    const float* __restrict__ Qre_in, const float* __restrict__ Qim_in,
    const float* __restrict__ Sprev,
    float* __restrict__ Qre_out, float* __restrict__ Qim_out,
    float* __restrict__ Sout)
{
    const int gid = blockIdx.x * 256 + threadIdx.x;
    const int g   = gid >> 3;          // (b,f) index
    const int kp  = gid & 7;           // row owned (6,7 inactive dupes of 5)
    if (g >= BFQ) return;
    const int b  = g / FQ;
    const int kk = kp < 6 ? kp : 5;

    // V[kk] (6x6 complex): 18 float4 loads, unpacked in place
    const float4* Vp4 = reinterpret_cast<const float4*>(V + (size_t)g * 432 + (size_t)kk * 72);
    float Vr[36], Vi[36];
#pragma unroll
    for (int e = 0; e < 18; e++) {
        const float4 t = Vp4[e];
        Vr[2*e] = t.x; Vi[2*e] = t.y; Vr[2*e+1] = t.z; Vi[2*e+1] = t.w;
    }

    float Qr[6], Qi[6];
    const float* qrp = Qre_in + (size_t)g * 36 + kk * 6;
    const float* qip = Qim_in + (size_t)g * 36 + kk * 6;
#pragma unroll
    for (int m = 0; m < 6; m++) { Qr[m] = qrp[m]; Qi[m] = qip[m]; }

    if (Sprev) {
        const float sc = Sprev[b] * (1.0f / (float)FMTQ);
        const float s  = rsqrtf(fmaxf(sc, 1e-6f));
#pragma unroll
        for (int m = 0; m < 6; m++) { Qr[m] *= s; Qi[m] *= s; }
    }

#pragma unroll
    for (int k = 0; k < 6; k++) {
        // q = current row k (pre-update copy), broadcast from lane k
        float qr[6], qi[6];
#pragma unroll
        for (int m = 0; m < 6; m++) {
            qr[m] = __shfl(Qr[m], k, 8);
            qi[m] = __shfl(Qi[m], k, 8);
        }
        // W[m] = sum_n V[kk][m][n] * conj(q[n])
        float Wr[6], Wi[6];
#pragma unroll
        for (int m = 0; m < 6; m++) {
            float wr = 0.0f, wi = 0.0f;
#pragma unroll
            for (int n = 0; n < 6; n++) {
                const float vr = Vr[m * 6 + n], vi = Vi[m * 6 + n];
                wr += vr * qr[n] + vi * qi[n];
                wi += vi * qr[n] - vr * qi[n];
            }
            Wr[m] = wr; Wi[m] = wi;
        }
        float qVq = 0.0f;
#pragma unroll
        for (int m = 0; m < 6; m++) qVq += qr[m] * Wr[m] - qi[m] * Wi[m];
        qVq = fmaxf(qVq, 1e-6f);

        float vr, vi;
        if (kp == k) {
            vr = 1.0f - rsqrtf(qVq);    // v[k] = 1 - qVq^(-1/2)
            vi = 0.0f;
        } else {
            float nr = 0.0f, ni = 0.0f;
#pragma unroll
            for (int m = 0; m < 6; m++) {
                nr += Qr[m] * Wr[m] - Qi[m] * Wi[m];
                ni += Qr[m] * Wi[m] + Qi[m] * Wr[m];
            }
            const float inv = 1.0f / qVq;
            vr = nr * inv; vi = ni * inv;
        }
#pragma unroll
        for (int m = 0; m < 6; m++) {
            Qr[m] -= vr * qr[m] - vi * qi[m];
            Qi[m] -= vr * qi[m] + vi * qr[m];
        }
    }

    // trace partial: row kk contribution to sum_m Q_m C Q_m^H
    // C consumed row-by-row straight from the float4 loads.
    const float4* Cp4 = reinterpret_cast<const float4*>(Cw + (size_t)g * 72);
    float trr = 0.0f;
#pragma unroll
    for (int m = 0; m < 6; m++) {
        float4 cb[3];
#pragma unroll
        for (int e = 0; e < 3; e++) cb[e] = Cp4[3 * m + e];
        float wr = 0.0f, wi = 0.0f;
#pragma unroll
        for (int n = 0; n < 6; n++) {
            const float cr = f4c(cb[n >> 1], (n & 1) * 2);
            const float ci = f4c(cb[n >> 1], (n & 1) * 2 + 1);
            wr += cr * Qr[n] + ci * Qi[n];     // C[m][n] * conj(Q[n])
            wi += ci * Qr[n] - cr * Qi[n];
        }
        trr += Qr[m] * wr - Qi[m] * wi;        // Re( Q[m] * w[m] )
    }
    if (kp >= 6) trr = 0.0f;
    trr += __shfl_xor(trr, 1, 8);
    trr += __shfl_xor(trr, 2, 8);
    trr += __shfl_xor(trr, 4, 8);
    if (kp == 0) atomicAdd(&Sout[b], trr);

    if (kp < 6) {
        float* qro = Qre_out + (size_t)g * 36 + kp * 6;
        float* qio = Qim_out + (size_t)g * 36 + kp * 6;
#pragma unroll
        for (int m = 0; m < 6; m++) { qro[m] = Qr[m]; qio[m] = Qi[m]; }
    }
}

// ---------------------------------------------------------------------------
// K3: xt[m,t] = |Q2 x|^2 / scale2   (float4 over t: 250 cols, 1 per thread)
// + fused Q-output: Q_final = Q2 / sqrt(clip(scale2,1e-6)), planar.
// R4: Q unpacked directly from float4 loads (no staging arrays).
// ---------------------------------------------------------------------------
__global__ __launch_bounds__(256) void k_xt(
    const float* __restrict__ xre, const float* __restrict__ xim,
    const float* __restrict__ Q2r, const float* __restrict__ Q2i,
    const float* __restrict__ S2, float* __restrict__ out,
    float* __restrict__ outQre, float* __restrict__ outQim)
{
    const int bf = blockIdx.x;
    const int b  = bf / FQ;
    const float s2 = S2[b];

    // fused k_qout (threads 0..35 handle this block's 36 Q entries)
    if (threadIdx.x < 36) {
        const float sc = s2 * (1.0f / (float)FMTQ);
        const float s  = rsqrtf(fmaxf(sc, 1e-6f));
        const int j = bf * 36 + (int)threadIdx.x;
        outQre[j] = Q2r[j] * s;
        if (outQim) outQim[j] = Q2i[j] * s;
    }

    const float4* qr4 = reinterpret_cast<const float4*>(Q2r + (size_t)bf * 36);
    const float4* qi4 = reinterpret_cast<const float4*>(Q2i + (size_t)bf * 36);
    float Qr[36], Qi[36];
#pragma unroll
    for (int e = 0; e < 9; e++) {
        const float4 a = qr4[e];
        Qr[4*e] = a.x; Qr[4*e+1] = a.y; Qr[4*e+2] = a.z; Qr[4*e+3] = a.w;
        const float4 c = qi4[e];
        Qi[4*e] = c.x; Qi[4*e+1] = c.y; Qi[4*e+2] = c.z; Qi[4*e+3] = c.w;
    }
    const float inv_scale = (float)FMTQ / s2;

    const int i = threadIdx.x;
    if (i < T4Q) {
        const float4* xr4 = reinterpret_cast<const float4*>(xre + (size_t)bf * MQ * TQ);
        const float4* xi4 = reinterpret_cast<const float4*>(xim + (size_t)bf * MQ * TQ);
        float ar[6][4], ai[6][4];
#pragma unroll
        for (int n = 0; n < 6; n++) {
            const float4 a = xr4[n * T4Q + i];
            ar[n][0] = a.x; ar[n][1] = a.y; ar[n][2] = a.z; ar[n][3] = a.w;
            const float4 c = xi4[n * T4Q + i];
            ai[n][0] = c.x; ai[n][1] = c.y; ai[n][2] = c.z; ai[n][3] = c.w;
        }
        float4* op4 = reinterpret_cast<float4*>(out + (size_t)bf * MQ * TQ);
#pragma unroll
        for (int m = 0; m < 6; m++) {
            float res[4];
#pragma unroll
            for (int e = 0; e < 4; e++) {
                float cr = 0.0f, ci = 0.0f;
#pragma unroll
                for (int n = 0; n < 6; n++) {
                    const float wr = Qr[m * 6 + n], wi = Qi[m * 6 + n];
                    cr += wr * ar[n][e] - wi * ai[n][e];
                    ci += wr * ai[n][e] + wi * ar[n][e];
                }
                res[e] = (cr * cr + ci * ci) * inv_scale;
            }
            op4[m * T4Q + i] = make_float4(res[0], res[1], res[2], res[3]);
        }
    }
}

// ---------------------------------------------------------------------------
extern "C" void kernel_launch(void* const* d_in, const int* in_sizes, int n_in,
                              void* d_out, int out_size, void* d_ws, size_t ws_size,
                              hipStream_t stream)
{
    (void)in_sizes; (void)n_in; (void)ws_size;
    const float* r   = (const float*)d_in[0];
    const float* Qre = (const float*)d_in[1];
    const float* Qim = (const float*)d_in[2];
    const float* xre = (const float*)d_in[3];
    const float* xim = (const float*)d_in[4];

    // workspace layout (floats): V | C | Q1r | Q1i | Q2r | Q2i | S1[16] | S2[16]
    float* ws  = (float*)d_ws;
    float* V   = ws;                          // BFQ*432
    float* Cw  = V   + (size_t)BFQ * 432;     // BFQ*72
    float* Q1r = Cw  + (size_t)BFQ * 72;      // BFQ*36
    float* Q1i = Q1r + (size_t)BFQ * 36;
    float* Q2r = Q1i + (size_t)BFQ * 36;
    float* Q2i = Q2r + (size_t)BFQ * 36;
    float* S1  = Q2i + (size_t)BFQ * 36;      // 16
    float* S2  = S1 + 16;                     // 16

    // Output layout (PLANAR, verified R2): [Q_re plane | Q_im plane | xt]
    const long long xt_elems = (long long)BFQ * MQ * TQ;        // 24,672,000
    const long long q_elems  = (long long)out_size - xt_elems;  // 296,064 or 148,032
    float* out_qre = (float*)d_out;
    float* out_qim = (q_elems >= 2LL * BFQ * 36) ? out_qre + (size_t)BFQ * 36 : nullptr;
    float* out_xt  = out_qre + (size_t)(q_elems > 0 ? q_elems : 2LL * BFQ * 36);

    k_stats<<<BFQ, 256, 0, stream>>>(r, xre, xim, V, Cw, S1);
    const int iterGrid = (BFQ * 8 + 255) / 256;
    k_iter<<<iterGrid, 256, 0, stream>>>(V, Cw, Qre, Qim, nullptr, Q1r, Q1i, S1);
    k_iter<<<iterGrid, 256, 0, stream>>>(V, Cw, Q1r, Q1i, S1, Q2r, Q2i, S2);
    k_xt<<<BFQ, 256, 0, stream>>>(xre, xim, Q2r, Q2i, S2, out_xt, out_qre, out_qim);
}

// Round 6
// 548.660 us; speedup vs baseline: 1.0515x; 1.0515x over previous
//
#include <hip/hip_runtime.h>

// Problem constants (from reference): B=16, F=257, M=6, T=1000, N_ITER=2
#define BQ 16
#define FQ 257
#define MQ 6
#define TQ 1000
#define T4Q 250                  // TQ/4 float4 columns per row (4000B rows, 16B aligned)
#define BFQ (BQ * FQ)            // 4112 independent (b,f) problems
#define FMTQ (FQ * MQ * TQ)      // 1,542,000  (divisor for per-batch scale mean)

#define CHUNK 64                 // float4 cols staged per chunk
#define NROWS 18                 // 6 r + 6 xre + 6 xim rows

__device__ __forceinline__ float wave_sum(float v) {
    v += __shfl_xor(v, 1);  v += __shfl_xor(v, 2);  v += __shfl_xor(v, 4);
    v += __shfl_xor(v, 8);  v += __shfl_xor(v, 16); v += __shfl_xor(v, 32);
    return v;
}

// compile-time float4 component select (folds under #pragma unroll)
__device__ __forceinline__ float f4c(const float4 v, int e) {
    return e == 0 ? v.x : e == 1 ? v.y : e == 2 ? v.z : v.w;
}

// ---------------------------------------------------------------------------
// K1 (k_stats): per (b,f):
//   V[k][m][n] = (1/T) sum_t r[k,t] * x[m,t] * conj(x[n,t])  + eps on diagonal
//   C[m][n]    =        sum_t x[m,t] * conj(x[n,t])
// R5/R6 structure (diagnosis: latency-bound, VALU 28%, HBM 13%, occ 19% in
// R2; R4's register-pipeline made it WORSE by halving occupancy):
//  - per t-chunk, the block stages all 18 rows x 64 float4 into LDS ONCE via
//    global_load_lds (width 16; LDS dest = wave-uniform base + lane*16 -> our
//    [row][col=lane] layout matches exactly; zero VGPR cost)
//  - double-buffered 2-phase: stage(c+1) issued before compute of chunk c;
//    one __syncthreads per chunk drains vmcnt under ~800cy of VALU
//  - kills the 4x/2.7x redundant per-wave global reads of r/x
//  - R6 FIX: chunk c is computed from buf[c & 1] (R5 passed the CHUNK index
//    as the BUFFER index -> compute(2)/compute(3) read out-of-bounds LDS,
//    chunks 2-3 lost -> absmax 0.367 fail)
// Pair partition = R3's VERIFIED 63-acc/wave split ((1,4) halved re/im);
// reduction = R2's verified butterfly; epilogue = lane-0 stores (R2 style,
// extended for the half-pair modes).
//   W0: D(0)(1)(2) + F(0,1)(0,2)(1,2)            63 acc
//   W1: D(3)(4)(5) + F(3,4)(3,5)(4,5)            63 acc
//   W2: F(0,3)(0,4)(0,5)(1,3) + Re-half(1,4)     63 acc
//   W3: F(1,5)(2,3)(2,4)(2,5) + Im-half(1,4)     63 acc
// mode md: 0=diag, 1=full off-diag, 2=re-half, 3=im-half
// ---------------------------------------------------------------------------
template<int W> struct PL;
template<> struct PL<0> { static constexpr int np = 6;
    static constexpr int pm[6] = {0,1,2,0,0,1};
    static constexpr int pn[6] = {0,1,2,1,2,2};
    static constexpr int md[6] = {0,0,0,1,1,1}; };
template<> struct PL<1> { static constexpr int np = 6;
    static constexpr int pm[6] = {3,4,5,3,3,4};
    static constexpr int pn[6] = {3,4,5,4,5,5};
    static constexpr int md[6] = {0,0,0,1,1,1}; };
template<> struct PL<2> { static constexpr int np = 5;
    static constexpr int pm[6] = {0,0,0,1,1,0};
    static constexpr int pn[6] = {3,4,5,3,4,0};
    static constexpr int md[6] = {1,1,1,1,2,0}; };
template<> struct PL<3> { static constexpr int np = 5;
    static constexpr int pm[6] = {1,2,2,2,1,0};
    static constexpr int pn[6] = {5,3,4,5,4,0};
    static constexpr int md[6] = {1,1,1,1,3,0}; };

template<int W> __device__ constexpr unsigned rowMaskFn() {
    unsigned msk = 0;
    for (int p = 0; p < PL<W>::np; p++) {
        msk |= 1u << PL<W>::pm[p];
        msk |= 1u << PL<W>::pn[p];
    }
    return msk;
}

template<int W>
__device__ __forceinline__ void stats_work(
    int bf, int w, int lane, const float* __restrict__ rp,
    const float* __restrict__ xrp, const float* __restrict__ xip,
    float4 (*buf)[NROWS][CHUNK],              // [2][18][64] shared
    float* __restrict__ V, float* __restrict__ Cw)
{
    constexpr int NP = PL<W>::np;
    constexpr unsigned rowmask = rowMaskFn<W>();

    float Vre[NP][6], Vim[NP][6], Cre[NP], Cim[NP];
#pragma unroll
    for (int p = 0; p < NP; p++) {
        Cre[p] = 0.0f; Cim[p] = 0.0f;
#pragma unroll
        for (int k = 0; k < 6; k++) { Vre[p][k] = 0.0f; Vim[p][k] = 0.0f; }
    }

    const float4* rp4  = reinterpret_cast<const float4*>(rp);
    const float4* xrp4 = reinterpret_cast<const float4*>(xrp);
    const float4* xip4 = reinterpret_cast<const float4*>(xip);

    // stage chunk c into buf[c&1]: wave w loads rows {w, w+4, w+8, w+12} and
    // (w<2) rows {16+w}. LDS dest is wave-uniform row base; HW scatters
    // lane*16. Tail cols clamped (duplicates never read by compute guard).
    auto stage = [&](int c) {
        const int b = c & 1;
        int col = c * CHUNK + lane;
        if (col > T4Q - 1) col = T4Q - 1;
#pragma unroll
        for (int s = 0; s < 5; s++) {
            if (s < 4 || w < 2) {
                const int row = w + 4 * s;
                const float4* src =
                    (row < 6  ? rp4  + row        * T4Q :
                     row < 12 ? xrp4 + (row - 6)  * T4Q :
                                xip4 + (row - 12) * T4Q) + col;
                __builtin_amdgcn_global_load_lds(
                    (const __attribute__((address_space(1))) void*)src,
                    (__attribute__((address_space(3))) void*)&buf[b][row][0],
                    16, 0, 0);
            }
        }
    };

    // compute chunk c from buf[c&1]
    auto compute = [&](int c) {
        const int b = c & 1;
        float4 R[6], XR[6], XI[6];
#pragma unroll
        for (int k = 0; k < 6; k++) R[k] = buf[b][k][lane];
#pragma unroll
        for (int row = 0; row < 6; row++) {
            if (rowmask & (1u << row)) {           // compile-time folded
                XR[row] = buf[b][6 + row][lane];
                XI[row] = buf[b][12 + row][lane];
            }
        }
#pragma unroll
        for (int e = 0; e < 4; e++) {
#pragma unroll
            for (int p = 0; p < NP; p++) {
                const int m = PL<W>::pm[p], n = PL<W>::pn[p];
                const int md = PL<W>::md[p];
                if (md == 0) {                       // diag
                    const float arm = f4c(XR[m], e), aim = f4c(XI[m], e);
                    const float pr = arm * arm + aim * aim;
                    Cre[p] += pr;
#pragma unroll
                    for (int k = 0; k < 6; k++) Vre[p][k] += f4c(R[k], e) * pr;
                } else if (md == 1) {                // full off-diag
                    const float arm = f4c(XR[m], e), aim = f4c(XI[m], e);
                    const float arn = f4c(XR[n], e), ain = f4c(XI[n], e);
                    const float pr = arm * arn + aim * ain;
                    const float pi = aim * arn - arm * ain;
                    Cre[p] += pr;  Cim[p] += pi;
#pragma unroll
                    for (int k = 0; k < 6; k++) {
                        const float rk = f4c(R[k], e);
                        Vre[p][k] += rk * pr;
                        Vim[p][k] += rk * pi;
                    }
                } else if (md == 2) {                // re-half of (m,n)
                    const float arm = f4c(XR[m], e), aim = f4c(XI[m], e);
                    const float arn = f4c(XR[n], e), ain = f4c(XI[n], e);
                    const float pr = arm * arn + aim * ain;
                    Cre[p] += pr;
#pragma unroll
                    for (int k = 0; k < 6; k++) Vre[p][k] += f4c(R[k], e) * pr;
                } else {                             // im-half of (m,n)
                    const float arm = f4c(XR[m], e), aim = f4c(XI[m], e);
                    const float arn = f4c(XR[n], e), ain = f4c(XI[n], e);
                    const float pi = aim * arn - arm * ain;
                    Cim[p] += pi;
#pragma unroll
                    for (int k = 0; k < 6; k++) Vim[p][k] += f4c(R[k], e) * pi;
                }
            }
        }
    };

    // 2-phase double-buffered pipeline over 4 chunks (cols 0..249).
    // Every wave executes the identical barrier sequence (branches are
    // wave-aligned), so barriers inside the switch are safe on CDNA.
    stage(0);
    __syncthreads();              // buf0 (chunk0) ready (drains vmcnt)
    stage(1);                     // buf1 in flight under compute(0)
    compute(0);                   // chunk0 <- buf0
    __syncthreads();              // buf1 (chunk1) ready; all waves done buf0
    stage(2);                     // buf0 in flight under compute(1)
    compute(1);                   // chunk1 <- buf1
    __syncthreads();              // buf0 (chunk2) ready; all waves done buf1
    stage(3);                     // buf1 in flight under compute(2)
    compute(2);                   // chunk2 <- buf0
    __syncthreads();              // buf1 (chunk3) ready
    if (lane < T4Q - 3 * CHUNK) compute(3);   // chunk3 <- buf1, lanes 0..57

    // butterfly-reduce this wave's accumulators (R2 verified)
#pragma unroll
    for (int p = 0; p < NP; p++) {
        const int md = PL<W>::md[p];
        if (md != 3) Cre[p] = wave_sum(Cre[p]);
        if (md == 1 || md == 3) Cim[p] = wave_sum(Cim[p]);
#pragma unroll
        for (int k = 0; k < 6; k++) {
            if (md != 3) Vre[p][k] = wave_sum(Vre[p][k]);
            if (md == 1 || md == 3) Vim[p][k] = wave_sum(Vim[p][k]);
        }
    }

    if (lane == 0) {
        const float invT = 1.0f / (float)TQ;
        float*  Vf = V  + (size_t)bf * 432;
        float*  Cf = Cw + (size_t)bf * 72;
        float2* Vg = reinterpret_cast<float2*>(Vf);
        float2* Cg = reinterpret_cast<float2*>(Cf);
#pragma unroll
        for (int p = 0; p < NP; p++) {
            const int m = PL<W>::pm[p], n = PL<W>::pn[p];
            const int md = PL<W>::md[p];
            if (md == 0) {
#pragma unroll
                for (int k = 0; k < 6; k++)
                    Vg[k * 36 + m * 6 + m] = make_float2(Vre[p][k] * invT + 1e-6f, 0.0f);
                Cg[m * 6 + m] = make_float2(Cre[p], 0.0f);
            } else if (md == 1) {
#pragma unroll
                for (int k = 0; k < 6; k++) {
                    const float re = Vre[p][k] * invT, im = Vim[p][k] * invT;
                    Vg[k * 36 + m * 6 + n] = make_float2(re,  im);
                    Vg[k * 36 + n * 6 + m] = make_float2(re, -im);
                }
                Cg[m * 6 + n] = make_float2(Cre[p],  Cim[p]);
                Cg[n * 6 + m] = make_float2(Cre[p], -Cim[p]);
            } else if (md == 2) {                   // re components only
#pragma unroll
                for (int k = 0; k < 6; k++) {
                    const float re = Vre[p][k] * invT;
                    Vf[k * 72 + m * 12 + n * 2] = re;
                    Vf[k * 72 + n * 12 + m * 2] = re;
                }
                Cf[m * 12 + n * 2] = Cre[p];
                Cf[n * 12 + m * 2] = Cre[p];
            } else {                                // im components only
#pragma unroll
                for (int k = 0; k < 6; k++) {
                    const float im = Vim[p][k] * invT;
                    Vf[k * 72 + m * 12 + n * 2 + 1] =  im;
                    Vf[k * 72 + n * 12 + m * 2 + 1] = -im;
                }
                Cf[m * 12 + n * 2 + 1] =  Cim[p];
                Cf[n * 12 + m * 2 + 1] = -Cim[p];
            }
        }
    }
}

__global__ __launch_bounds__(256) void k_stats(
    const float* __restrict__ r, const float* __restrict__ xre,
    const float* __restrict__ xim, float* __restrict__ V,
    float* __restrict__ Cw, float* __restrict__ S)
{
    __shared__ float4 buf[2][NROWS][CHUNK];   // 36,864 B
    const int bf   = blockIdx.x;
    const int w    = threadIdx.x >> 6;
    const int lane = threadIdx.x & 63;
    // fused k_zero: S1[16]|S2[16] contiguous; done before any k_iter atomics
    // (stream order guarantees visibility).
    if (bf == 0 && threadIdx.x < 32) S[threadIdx.x] = 0.0f;
    const float* rp  = r   + (size_t)bf * MQ * TQ;
    const float* xrp = xre + (size_t)bf * MQ * TQ;
    const float* xip = xim + (size_t)bf * MQ * TQ;
    switch (w) {
        case 0:  stats_work<0>(bf, w, lane, rp, xrp, xip, buf, V, Cw); break;
        case 1:  stats_work<1>(bf, w, lane, rp, xrp, xip, buf, V, Cw); break;
        case 2:  stats_work<2>(bf, w, lane, rp, xrp, xip, buf, V, Cw); break;
        default: stats_work<3>(bf, w, lane, rp, xrp, xip, buf, V, Cw); break;
    }
}

// ---------------------------------------------------------------------------
// K2: one ISS iteration (6 sequential k-steps) + trace(Q C Q^H) partial for
// the per-batch scale. 8 lanes per (b,f): lane kp<6 owns row kp of Q and
// V[kp]; pivot row q broadcast via width-8 shuffles.  (R4, verified)
// ---------------------------------------------------------------------------
__global__ __launch_bounds__(256) void k_iter(
    const float* __restrict__ V, const float* __restrict__ Cw,
    const float* __restrict__ Qre_in, const float* __restrict__ Qim_in,
    const float* __restrict__ Sprev,
    float* __restrict__ Qre_out, float* __restrict__ Qim_out,
    float* __restrict__ Sout)
{
    const int gid = blockIdx.x * 256 + threadIdx.x;
    const int g   = gid >> 3;          // (b,f) index
    const int kp  = gid & 7;           // row owned (6,7 inactive dupes of 5)
    if (g >= BFQ) return;
    const int b  = g / FQ;
    const int kk = kp < 6 ? kp : 5;

    // V[kk] (6x6 complex): 18 float4 loads, unpacked in place
    const float4* Vp4 = reinterpret_cast<const float4*>(V + (size_t)g * 432 + (size_t)kk * 72);
    float Vr[36], Vi[36];
#pragma unroll
    for (int e = 0; e < 18; e++) {
        const float4 t = Vp4[e];
        Vr[2*e] = t.x; Vi[2*e] = t.y; Vr[2*e+1] = t.z; Vi[2*e+1] = t.w;
    }

    float Qr[6], Qi[6];
    const float* qrp = Qre_in + (size_t)g * 36 + kk * 6;
    const float* qip = Qim_in + (size_t)g * 36 + kk * 6;
#pragma unroll
    for (int m = 0; m < 6; m++) { Qr[m] = qrp[m]; Qi[m] = qip[m]; }

    if (Sprev) {
        const float sc = Sprev[b] * (1.0f / (float)FMTQ);
        const float s  = rsqrtf(fmaxf(sc, 1e-6f));
#pragma unroll
        for (int m = 0; m < 6; m++) { Qr[m] *= s; Qi[m] *= s; }
    }

#pragma unroll
    for (int k = 0; k < 6; k++) {
        // q = current row k (pre-update copy), broadcast from lane k
        float qr[6], qi[6];
#pragma unroll
        for (int m = 0; m < 6; m++) {
            qr[m] = __shfl(Qr[m], k, 8);
            qi[m] = __shfl(Qi[m], k, 8);
        }
        // W[m] = sum_n V[kk][m][n] * conj(q[n])
        float Wr[6], Wi[6];
#pragma unroll
        for (int m = 0; m < 6; m++) {
            float wr = 0.0f, wi = 0.0f;
#pragma unroll
            for (int n = 0; n < 6; n++) {
                const float vr = Vr[m * 6 + n], vi = Vi[m * 6 + n];
                wr += vr * qr[n] + vi * qi[n];
                wi += vi * qr[n] - vr * qi[n];
            }
            Wr[m] = wr; Wi[m] = wi;
        }
        float qVq = 0.0f;
#pragma unroll
        for (int m = 0; m < 6; m++) qVq += qr[m] * Wr[m] - qi[m] * Wi[m];
        qVq = fmaxf(qVq, 1e-6f);

        float vr, vi;
        if (kp == k) {
            vr = 1.0f - rsqrtf(qVq);    // v[k] = 1 - qVq^(-1/2)
            vi = 0.0f;
        } else {
            float nr = 0.0f, ni = 0.0f;
#pragma unroll
            for (int m = 0; m < 6; m++) {
                nr += Qr[m] * Wr[m] - Qi[m] * Wi[m];
                ni += Qr[m] * Wi[m] + Qi[m] * Wr[m];
            }
            const float inv = 1.0f / qVq;
            vr = nr * inv; vi = ni * inv;
        }
#pragma unroll
        for (int m = 0; m < 6; m++) {
            Qr[m] -= vr * qr[m] - vi * qi[m];
            Qi[m] -= vr * qi[m] + vi * qr[m];
        }
    }

    // trace partial: row kk contribution to sum_m Q_m C Q_m^H
    // C consumed row-by-row straight from the float4 loads.
    const float4* Cp4 = reinterpret_cast<const float4*>(Cw + (size_t)g * 72);
    float trr = 0.0f;
#pragma unroll
    for (int m = 0; m < 6; m++) {
        float4 cb[3];
#pragma unroll
        for (int e = 0; e < 3; e++) cb[e] = Cp4[3 * m + e];
        float wr = 0.0f, wi = 0.0f;
#pragma unroll
        for (int n = 0; n < 6; n++) {
            const float cr = f4c(cb[n >> 1], (n & 1) * 2);
            const float ci = f4c(cb[n >> 1], (n & 1) * 2 + 1);
            wr += cr * Qr[n] + ci * Qi[n];     // C[m][n] * conj(Q[n])
            wi += ci * Qr[n] - cr * Qi[n];
        }
        trr += Qr[m] * wr - Qi[m] * wi;        // Re( Q[m] * w[m] )
    }
    if (kp >= 6) trr = 0.0f;
    trr += __shfl_xor(trr, 1, 8);
    trr += __shfl_xor(trr, 2, 8);
    trr += __shfl_xor(trr, 4, 8);
    if (kp == 0) atomicAdd(&Sout[b], trr);

    if (kp < 6) {
        float* qro = Qre_out + (size_t)g * 36 + kp * 6;
        float* qio = Qim_out + (size_t)g * 36 + kp * 6;
#pragma unroll
        for (int m = 0; m < 6; m++) { qro[m] = Qr[m]; qio[m] = Qi[m]; }
    }
}

// ---------------------------------------------------------------------------
// K3: xt[m,t] = |Q2 x|^2 / scale2   (float4 over t: 250 cols, 1 per thread)
// + fused Q-output: Q_final = Q2 / sqrt(clip(scale2,1e-6)), planar.
// (R4, verified)
// ---------------------------------------------------------------------------
__global__ __launch_bounds__(256) void k_xt(
    const float* __restrict__ xre, const float* __restrict__ xim,
    const float* __restrict__ Q2r, const float* __restrict__ Q2i,
    const float* __restrict__ S2, float* __restrict__ out,
    float* __restrict__ outQre, float* __restrict__ outQim)
{
    const int bf = blockIdx.x;
    const int b  = bf / FQ;
    const float s2 = S2[b];

    // fused k_qout (threads 0..35 handle this block's 36 Q entries)
    if (threadIdx.x < 36) {
        const float sc = s2 * (1.0f / (float)FMTQ);
        const float s  = rsqrtf(fmaxf(sc, 1e-6f));
        const int j = bf * 36 + (int)threadIdx.x;
        outQre[j] = Q2r[j] * s;
        if (outQim) outQim[j] = Q2i[j] * s;
    }

    const float4* qr4 = reinterpret_cast<const float4*>(Q2r + (size_t)bf * 36);
    const float4* qi4 = reinterpret_cast<const float4*>(Q2i + (size_t)bf * 36);
    float Qr[36], Qi[36];
#pragma unroll
    for (int e = 0; e < 9; e++) {
        const float4 a = qr4[e];
        Qr[4*e] = a.x; Qr[4*e+1] = a.y; Qr[4*e+2] = a.z; Qr[4*e+3] = a.w;
        const float4 c = qi4[e];
        Qi[4*e] = c.x; Qi[4*e+1] = c.y; Qi[4*e+2] = c.z; Qi[4*e+3] = c.w;
    }
    const float inv_scale = (float)FMTQ / s2;

    const int i = threadIdx.x;
    if (i < T4Q) {
        const float4* xr4 = reinterpret_cast<const float4*>(xre + (size_t)bf * MQ * TQ);
        const float4* xi4 = reinterpret_cast<const float4*>(xim + (size_t)bf * MQ * TQ);
        float ar[6][4], ai[6][4];
#pragma unroll
        for (int n = 0; n < 6; n++) {
            const float4 a = xr4[n * T4Q + i];
            ar[n][0] = a.x; ar[n][1] = a.y; ar[n][2] = a.z; ar[n][3] = a.w;
            const float4 c = xi4[n * T4Q + i];
            ai[n][0] = c.x; ai[n][1] = c.y; ai[n][2] = c.z; ai[n][3] = c.w;
        }
        float4* op4 = reinterpret_cast<float4*>(out + (size_t)bf * MQ * TQ);
#pragma unroll
        for (int m = 0; m < 6; m++) {
            float res[4];
#pragma unroll
            for (int e = 0; e < 4; e++) {
                float cr = 0.0f, ci = 0.0f;
#pragma unroll
                for (int n = 0; n < 6; n++) {
                    const float wr = Qr[m * 6 + n], wi = Qi[m * 6 + n];
                    cr += wr * ar[n][e] - wi * ai[n][e];
                    ci += wr * ai[n][e] + wi * ar[n][e];
                }
                res[e] = (cr * cr + ci * ci) * inv_scale;
            }
            op4[m * T4Q + i] = make_float4(res[0], res[1], res[2], res[3]);
        }
    }
}

// ---------------------------------------------------------------------------
extern "C" void kernel_launch(void* const* d_in, const int* in_sizes, int n_in,
                              void* d_out, int out_size, void* d_ws, size_t ws_size,
                              hipStream_t stream)
{
    (void)in_sizes; (void)n_in; (void)ws_size;
    const float* r   = (const float*)d_in[0];
    const float* Qre = (const float*)d_in[1];
    const float* Qim = (const float*)d_in[2];
    const float* xre = (const float*)d_in[3];
    const float* xim = (const float*)d_in[4];

    // workspace layout (floats): V | C | Q1r | Q1i | Q2r | Q2i | S1[16] | S2[16]
    float* ws  = (float*)d_ws;
    float* V   = ws;                          // BFQ*432
    float* Cw  = V   + (size_t)BFQ * 432;     // BFQ*72
    float* Q1r = Cw  + (size_t)BFQ * 72;      // BFQ*36
    float* Q1i = Q1r + (size_t)BFQ * 36;
    float* Q2r = Q1i + (size_t)BFQ * 36;
    float* Q2i = Q2r + (size_t)BFQ * 36;
    float* S1  = Q2i + (size_t)BFQ * 36;      // 16
    float* S2  = S1 + 16;                     // 16

    // Output layout (PLANAR, verified R2): [Q_re plane | Q_im plane | xt]
    const long long xt_elems = (long long)BFQ * MQ * TQ;        // 24,672,000
    const long long q_elems  = (long long)out_size - xt_elems;  // 296,064 or 148,032
    float* out_qre = (float*)d_out;
    float* out_qim = (q_elems >= 2LL * BFQ * 36) ? out_qre + (size_t)BFQ * 36 : nullptr;
    float* out_xt  = out_qre + (size_t)(q_elems > 0 ? q_elems : 2LL * BFQ * 36);

    k_stats<<<BFQ, 256, 0, stream>>>(r, xre, xim, V, Cw, S1);
    const int iterGrid = (BFQ * 8 + 255) / 256;
    k_iter<<<iterGrid, 256, 0, stream>>>(V, Cw, Qre, Qim, nullptr, Q1r, Q1i, S1);
    k_iter<<<iterGrid, 256, 0, stream>>>(V, Cw, Q1r, Q1i, S1, Q2r, Q2i, S2);
    k_xt<<<BFQ, 256, 0, stream>>>(xre, xim, Q2r, Q2i, S2, out_xt, out_qre, out_qim);
}

// Round 8
// 420.356 us; speedup vs baseline: 1.3725x; 1.3052x over previous
//
#include <hip/hip_runtime.h>

// Problem constants (from reference): B=16, F=257, M=6, T=1000, N_ITER=2
#define BQ 16
#define FQ 257
#define MQ 6
#define TQ 1000
#define T4Q 250                  // TQ/4 float4 columns per row (4000B rows, 16B aligned)
#define BFQ (BQ * FQ)            // 4112 independent (b,f) problems
#define FMTQ (FQ * MQ * TQ)      // 1,542,000  (divisor for per-batch scale mean)

__device__ __forceinline__ float wave_sum(float v) {
    v += __shfl_xor(v, 1);  v += __shfl_xor(v, 2);  v += __shfl_xor(v, 4);
    v += __shfl_xor(v, 8);  v += __shfl_xor(v, 16); v += __shfl_xor(v, 32);
    return v;
}

// compile-time float4 component select (folds under #pragma unroll)
__device__ __forceinline__ float f4c(const float4 v, int e) {
    return e == 0 ? v.x : e == 1 ? v.y : e == 2 ? v.z : v.w;
}

// ---------------------------------------------------------------------------
// K0: zero the 32 scale accumulators (S1[16], S2[16] contiguous).
// MUST be a kernel (not hipMemsetAsync): R7 showed the harness's graph
// capture does not replay the memset -> S accumulated across replays ->
// post-timing divergence. A kernel node always replays.
// ---------------------------------------------------------------------------
__global__ void k_zero(float* __restrict__ S) {
    if (threadIdx.x < 32) S[threadIdx.x] = 0.0f;
}

// ---------------------------------------------------------------------------
// K1 (k_stats + fused iter1): per (b,f):
//   V[k][m][n] = (1/T) sum_t r[k,t] * x[m,t] * conj(x[n,t])  + eps on diag
//   C[m][n]    =        sum_t x[m,t] * conj(x[n,t])
//   then ISS iteration 1 (lanes 0-7, V/C read from a 2KB LDS mirror).
// Stats body = R2-verified (150us, VGPR 88, occ 19.4%): float4 strided
// t-loop, butterfly reduce, lane-0 epilogue. R3/R4/R6 structural rewrites
// all regressed -> kept simple. iter1 fusion kills the standalone 129-block
// latency-bound k_iter1 dispatch and spreads its S1 atomics over ~150us.
// (R7 timed this structure at 463.8us before the replay-state bug.)
// Pair partition (21 Hermitian pairs, verified R2 — DO NOT EDIT):
//   W0: (0,0)(0,1)(0,2)(1,1)(1,2)(2,2)   rows {0,1,2}
//   W1: (3,3)(3,4)(3,5)(4,4)(4,5)(5,5)   rows {3,4,5}
//   W2: (0,3)(0,4)(0,5)(1,3)(1,4)        cross part 1
//   W3: (1,5)(2,3)(2,4)(2,5)             cross part 2
// ---------------------------------------------------------------------------
template<int W> struct PL;
template<> struct PL<0> { static constexpr int np = 6;
    static constexpr int pm[6] = {0,0,0,1,1,2};
    static constexpr int pn[6] = {0,1,2,1,2,2}; };
template<> struct PL<1> { static constexpr int np = 6;
    static constexpr int pm[6] = {3,3,3,4,4,5};
    static constexpr int pn[6] = {3,4,5,4,5,5}; };
template<> struct PL<2> { static constexpr int np = 5;
    static constexpr int pm[6] = {0,0,0,1,1,0};
    static constexpr int pn[6] = {3,4,5,3,4,0}; };
template<> struct PL<3> { static constexpr int np = 4;
    static constexpr int pm[6] = {1,2,2,2,0,0};
    static constexpr int pn[6] = {5,3,4,5,0,0}; };

template<int W> __device__ constexpr unsigned rowMaskFn() {
    unsigned msk = 0;
    for (int p = 0; p < PL<W>::np; p++) {
        msk |= 1u << PL<W>::pm[p];
        msk |= 1u << PL<W>::pn[p];
    }
    return msk;
}

template<int W>
__device__ __forceinline__ void stats_work(
    int bf, int lane, const float* __restrict__ rp,
    const float* __restrict__ xrp, const float* __restrict__ xip,
    float* __restrict__ V, float* __restrict__ Cw,
    float* __restrict__ Vl, float* __restrict__ Cl)   // LDS mirrors
{
    constexpr int NP = PL<W>::np;
    constexpr unsigned rowmask = rowMaskFn<W>();

    float Vre[NP][6], Vim[NP][6], Cre[NP], Cim[NP];
#pragma unroll
    for (int p = 0; p < NP; p++) {
        Cre[p] = 0.0f; Cim[p] = 0.0f;
#pragma unroll
        for (int k = 0; k < 6; k++) { Vre[p][k] = 0.0f; Vim[p][k] = 0.0f; }
    }

    const float4* rp4  = reinterpret_cast<const float4*>(rp);
    const float4* xrp4 = reinterpret_cast<const float4*>(xrp);
    const float4* xip4 = reinterpret_cast<const float4*>(xip);

#pragma unroll 1
    for (int i = lane; i < T4Q; i += 64) {
        float rr[6][4], ar[6][4], ai[6][4];
#pragma unroll
        for (int k = 0; k < 6; k++) {
            const float4 v = rp4[k * T4Q + i];
            rr[k][0] = v.x; rr[k][1] = v.y; rr[k][2] = v.z; rr[k][3] = v.w;
        }
#pragma unroll
        for (int row = 0; row < 6; row++) {
            if (rowmask & (1u << row)) {           // compile-time folded
                const float4 a = xrp4[row * T4Q + i];
                ar[row][0] = a.x; ar[row][1] = a.y; ar[row][2] = a.z; ar[row][3] = a.w;
                const float4 b = xip4[row * T4Q + i];
                ai[row][0] = b.x; ai[row][1] = b.y; ai[row][2] = b.z; ai[row][3] = b.w;
            }
        }
#pragma unroll
        for (int e = 0; e < 4; e++) {
#pragma unroll
            for (int p = 0; p < NP; p++) {
                const int m = PL<W>::pm[p], n = PL<W>::pn[p];
                if (m == n) {
                    const float pr = ar[m][e] * ar[m][e] + ai[m][e] * ai[m][e];
                    Cre[p] += pr;
#pragma unroll
                    for (int k = 0; k < 6; k++) Vre[p][k] += rr[k][e] * pr;
                } else {
                    const float pr = ar[m][e] * ar[n][e] + ai[m][e] * ai[n][e];
                    const float pi = ai[m][e] * ar[n][e] - ar[m][e] * ai[n][e];
                    Cre[p] += pr;  Cim[p] += pi;
#pragma unroll
                    for (int k = 0; k < 6; k++) {
                        Vre[p][k] += rr[k][e] * pr;
                        Vim[p][k] += rr[k][e] * pi;
                    }
                }
            }
        }
    }

    // butterfly-reduce this wave's accumulators (R2 verified)
#pragma unroll
    for (int p = 0; p < NP; p++) {
        const int m = PL<W>::pm[p], n = PL<W>::pn[p];
        Cre[p] = wave_sum(Cre[p]);
        if (m != n) Cim[p] = wave_sum(Cim[p]);
#pragma unroll
        for (int k = 0; k < 6; k++) {
            Vre[p][k] = wave_sum(Vre[p][k]);
            if (m != n) Vim[p][k] = wave_sum(Vim[p][k]);
        }
    }

    if (lane == 0) {
        const float invT = 1.0f / (float)TQ;
        float2* Vg = reinterpret_cast<float2*>(V + (size_t)bf * 432);
        float2* Cg = reinterpret_cast<float2*>(Cw + (size_t)bf * 72);
        float2* Vs = reinterpret_cast<float2*>(Vl);
        float2* Cs = reinterpret_cast<float2*>(Cl);
#pragma unroll
        for (int p = 0; p < NP; p++) {
            const int m = PL<W>::pm[p], n = PL<W>::pn[p];
            if (m == n) {
#pragma unroll
                for (int k = 0; k < 6; k++) {
                    const float2 d = make_float2(Vre[p][k] * invT + 1e-6f, 0.0f);
                    Vg[k * 36 + m * 6 + m] = d;
                    Vs[k * 36 + m * 6 + m] = d;
                }
                const float2 c = make_float2(Cre[p], 0.0f);
                Cg[m * 6 + m] = c;  Cs[m * 6 + m] = c;
            } else {
#pragma unroll
                for (int k = 0; k < 6; k++) {
                    const float re = Vre[p][k] * invT, im = Vim[p][k] * invT;
                    const float2 a = make_float2(re,  im);
                    const float2 b = make_float2(re, -im);
                    Vg[k * 36 + m * 6 + n] = a;  Vs[k * 36 + m * 6 + n] = a;
                    Vg[k * 36 + n * 6 + m] = b;  Vs[k * 36 + n * 6 + m] = b;
                }
                const float2 a = make_float2(Cre[p],  Cim[p]);
                const float2 b = make_float2(Cre[p], -Cim[p]);
                Cg[m * 6 + n] = a;  Cs[m * 6 + n] = a;
                Cg[n * 6 + m] = b;  Cs[n * 6 + m] = b;
            }
        }
    }
}

__global__ __launch_bounds__(256) void k_stats(
    const float* __restrict__ r, const float* __restrict__ xre,
    const float* __restrict__ xim, float* __restrict__ V,
    float* __restrict__ Cw,
    const float* __restrict__ Qre_in, const float* __restrict__ Qim_in,
    float* __restrict__ Q1r, float* __restrict__ Q1i,
    float* __restrict__ S1)
{
    __shared__ float Vl[432];
    __shared__ float Cl[72];
    const int bf   = blockIdx.x;
    const int w    = threadIdx.x >> 6;
    const int lane = threadIdx.x & 63;
    const float* rp  = r   + (size_t)bf * MQ * TQ;
    const float* xrp = xre + (size_t)bf * MQ * TQ;
    const float* xip = xim + (size_t)bf * MQ * TQ;
    switch (w) {
        case 0:  stats_work<0>(bf, lane, rp, xrp, xip, V, Cw, Vl, Cl); break;
        case 1:  stats_work<1>(bf, lane, rp, xrp, xip, V, Cw, Vl, Cl); break;
        case 2:  stats_work<2>(bf, lane, rp, xrp, xip, V, Cw, Vl, Cl); break;
        default: stats_work<3>(bf, lane, rp, xrp, xip, V, Cw, Vl, Cl); break;
    }

    __syncthreads();   // V/C mirrors complete (uniform barrier, all waves)

    // ---- fused ISS iteration 1: lanes 0-7 of wave 0, V/C from LDS ----
    if (threadIdx.x < 8) {
        const int kp = threadIdx.x;
        const int kk = kp < 6 ? kp : 5;
        float Vr[36], Vi[36];
#pragma unroll
        for (int j = 0; j < 36; ++j) {
            Vr[j] = Vl[kk * 72 + 2 * j];
            Vi[j] = Vl[kk * 72 + 2 * j + 1];
        }
        float Qr[6], Qi[6];
        const float* qrp = Qre_in + (size_t)bf * 36 + kk * 6;
        const float* qip = Qim_in + (size_t)bf * 36 + kk * 6;
#pragma unroll
        for (int m = 0; m < 6; m++) { Qr[m] = qrp[m]; Qi[m] = qip[m]; }

#pragma unroll
        for (int k = 0; k < 6; k++) {
            float qr[6], qi[6];
#pragma unroll
            for (int m = 0; m < 6; m++) {
                qr[m] = __shfl(Qr[m], k, 8);
                qi[m] = __shfl(Qi[m], k, 8);
            }
            float Wr[6], Wi[6];
#pragma unroll
            for (int m = 0; m < 6; m++) {
                float wr = 0.0f, wi = 0.0f;
#pragma unroll
                for (int n = 0; n < 6; n++) {
                    const float vr = Vr[m * 6 + n], vi = Vi[m * 6 + n];
                    wr += vr * qr[n] + vi * qi[n];
                    wi += vi * qr[n] - vr * qi[n];
                }
                Wr[m] = wr; Wi[m] = wi;
            }
            float qVq = 0.0f;
#pragma unroll
            for (int m = 0; m < 6; m++) qVq += qr[m] * Wr[m] - qi[m] * Wi[m];
            qVq = fmaxf(qVq, 1e-6f);

            float vr, vi;
            if (kp == k) {
                vr = 1.0f - rsqrtf(qVq);
                vi = 0.0f;
            } else {
                float nr = 0.0f, ni = 0.0f;
#pragma unroll
                for (int m = 0; m < 6; m++) {
                    nr += Qr[m] * Wr[m] - Qi[m] * Wi[m];
                    ni += Qr[m] * Wi[m] + Qi[m] * Wr[m];
                }
                const float inv = 1.0f / qVq;
                vr = nr * inv; vi = ni * inv;
            }
#pragma unroll
            for (int m = 0; m < 6; m++) {
                Qr[m] -= vr * qr[m] - vi * qi[m];
                Qi[m] -= vr * qi[m] + vi * qr[m];
            }
        }

        // trace partial from C (LDS)
        float trr = 0.0f;
#pragma unroll
        for (int m = 0; m < 6; m++) {
            float wr = 0.0f, wi = 0.0f;
#pragma unroll
            for (int n = 0; n < 6; n++) {
                const float cr = Cl[m * 12 + 2 * n];
                const float ci = Cl[m * 12 + 2 * n + 1];
                wr += cr * Qr[n] + ci * Qi[n];
                wi += ci * Qr[n] - cr * Qi[n];
            }
            trr += Qr[m] * wr - Qi[m] * wi;
        }
        if (kp >= 6) trr = 0.0f;
        trr += __shfl_xor(trr, 1, 8);
        trr += __shfl_xor(trr, 2, 8);
        trr += __shfl_xor(trr, 4, 8);
        if (kp == 0) atomicAdd(&S1[bf / FQ], trr);

        if (kp < 6) {
            float* qro = Q1r + (size_t)bf * 36 + kp * 6;
            float* qio = Q1i + (size_t)bf * 36 + kp * 6;
#pragma unroll
            for (int m = 0; m < 6; m++) { qro[m] = Qr[m]; qio[m] = Qi[m]; }
        }
    }
}

// ---------------------------------------------------------------------------
// K2 (k_iter, iteration 2): 8 lanes per (b,f); lane kp<6 owns row kp.
// R7: no early return (barrier-safe), block-level LDS reduction of the trace
// before atomics: <=2 distinct b per 32-group block -> 2 atomics/block
// (258 total vs 4112).
// ---------------------------------------------------------------------------
__global__ __launch_bounds__(256) void k_iter(
    const float* __restrict__ V, const float* __restrict__ Cw,
    const float* __restrict__ Qre_in, const float* __restrict__ Qim_in,
    const float* __restrict__ Sprev,
    float* __restrict__ Qre_out, float* __restrict__ Qim_out,
    float* __restrict__ Sout)
{
    __shared__ float sred[32];
    const int gid = blockIdx.x * 256 + threadIdx.x;
    const int g   = gid >> 3;          // (b,f) index
    const int kp  = gid & 7;           // row owned (6,7 inactive dupes of 5)
    const bool active = g < BFQ;
    const int ga  = active ? g : BFQ - 1;   // clamped for safe addresses
    const int b   = ga / FQ;
    const int kk  = kp < 6 ? kp : 5;

    // V[kk] (6x6 complex): 18 float4 loads, unpacked in place
    const float4* Vp4 = reinterpret_cast<const float4*>(V + (size_t)ga * 432 + (size_t)kk * 72);
    float Vr[36], Vi[36];
#pragma unroll
    for (int e = 0; e < 18; e++) {
        const float4 t = Vp4[e];
        Vr[2*e] = t.x; Vi[2*e] = t.y; Vr[2*e+1] = t.z; Vi[2*e+1] = t.w;
    }

    float Qr[6], Qi[6];
    const float* qrp = Qre_in + (size_t)ga * 36 + kk * 6;
    const float* qip = Qim_in + (size_t)ga * 36 + kk * 6;
#pragma unroll
    for (int m = 0; m < 6; m++) { Qr[m] = qrp[m]; Qi[m] = qip[m]; }

    {
        const float sc = Sprev[b] * (1.0f / (float)FMTQ);
        const float s  = rsqrtf(fmaxf(sc, 1e-6f));
#pragma unroll
        for (int m = 0; m < 6; m++) { Qr[m] *= s; Qi[m] *= s; }
    }

#pragma unroll
    for (int k = 0; k < 6; k++) {
        float qr[6], qi[6];
#pragma unroll
        for (int m = 0; m < 6; m++) {
            qr[m] = __shfl(Qr[m], k, 8);
            qi[m] = __shfl(Qi[m], k, 8);
        }
        float Wr[6], Wi[6];
#pragma unroll
        for (int m = 0; m < 6; m++) {
            float wr = 0.0f, wi = 0.0f;
#pragma unroll
            for (int n = 0; n < 6; n++) {
                const float vr = Vr[m * 6 + n], vi = Vi[m * 6 + n];
                wr += vr * qr[n] + vi * qi[n];
                wi += vi * qr[n] - vr * qi[n];
            }
            Wr[m] = wr; Wi[m] = wi;
        }
        float qVq = 0.0f;
#pragma unroll
        for (int m = 0; m < 6; m++) qVq += qr[m] * Wr[m] - qi[m] * Wi[m];
        qVq = fmaxf(qVq, 1e-6f);

        float vr, vi;
        if (kp == k) {
            vr = 1.0f - rsqrtf(qVq);
            vi = 0.0f;
        } else {
            float nr = 0.0f, ni = 0.0f;
#pragma unroll
            for (int m = 0; m < 6; m++) {
                nr += Qr[m] * Wr[m] - Qi[m] * Wi[m];
                ni += Qr[m] * Wi[m] + Qi[m] * Wr[m];
            }
            const float inv = 1.0f / qVq;
            vr = nr * inv; vi = ni * inv;
        }
#pragma unroll
        for (int m = 0; m < 6; m++) {
            Qr[m] -= vr * qr[m] - vi * qi[m];
            Qi[m] -= vr * qi[m] + vi * qr[m];
        }
    }

    // trace partial: row kk contribution to sum_m Q_m C Q_m^H
    const float4* Cp4 = reinterpret_cast<const float4*>(Cw + (size_t)ga * 72);
    float trr = 0.0f;
#pragma unroll
    for (int m = 0; m < 6; m++) {
        float4 cb[3];
#pragma unroll
        for (int e = 0; e < 3; e++) cb[e] = Cp4[3 * m + e];
        float wr = 0.0f, wi = 0.0f;
#pragma unroll
        for (int n = 0; n < 6; n++) {
            const float cr = f4c(cb[n >> 1], (n & 1) * 2);
            const float ci = f4c(cb[n >> 1], (n & 1) * 2 + 1);
            wr += cr * Qr[n] + ci * Qi[n];
            wi += ci * Qr[n] - cr * Qi[n];
        }
        trr += Qr[m] * wr - Qi[m] * wi;
    }
    if (kp >= 6 || !active) trr = 0.0f;
    trr += __shfl_xor(trr, 1, 8);
    trr += __shfl_xor(trr, 2, 8);
    trr += __shfl_xor(trr, 4, 8);
    if (kp == 0) sred[threadIdx.x >> 3] = trr;

    __syncthreads();
    if (threadIdx.x == 0) {
        const int g0 = blockIdx.x * 32;
        float acc = 0.0f;
        int bcur = (g0 < BFQ ? g0 : BFQ - 1) / FQ;
        for (int t = 0; t < 32; ++t) {
            const int gg = g0 + t;
            if (gg >= BFQ) break;
            const int bb = gg / FQ;
            if (bb != bcur) { atomicAdd(&Sout[bcur], acc); acc = 0.0f; bcur = bb; }
            acc += sred[t];
        }
        atomicAdd(&Sout[bcur], acc);
    }

    if (active && kp < 6) {
        float* qro = Qre_out + (size_t)ga * 36 + kp * 6;
        float* qio = Qim_out + (size_t)ga * 36 + kp * 6;
#pragma unroll
        for (int m = 0; m < 6; m++) { qro[m] = Qr[m]; qio[m] = Qi[m]; }
    }
}

// ---------------------------------------------------------------------------
// K3: xt[m,t] = |Q2 x|^2 / scale2   (float4 over t: 250 cols, 1 per thread)
// + fused Q-output: Q_final = Q2 / sqrt(clip(scale2,1e-6)), planar.
// (R4, verified)
// ---------------------------------------------------------------------------
__global__ __launch_bounds__(256) void k_xt(
    const float* __restrict__ xre, const float* __restrict__ xim,
    const float* __restrict__ Q2r, const float* __restrict__ Q2i,
    const float* __restrict__ S2, float* __restrict__ out,
    float* __restrict__ outQre, float* __restrict__ outQim)
{
    const int bf = blockIdx.x;
    const int b  = bf / FQ;
    const float s2 = S2[b];

    // fused k_qout (threads 0..35 handle this block's 36 Q entries)
    if (threadIdx.x < 36) {
        const float sc = s2 * (1.0f / (float)FMTQ);
        const float s  = rsqrtf(fmaxf(sc, 1e-6f));
        const int j = bf * 36 + (int)threadIdx.x;
        outQre[j] = Q2r[j] * s;
        if (outQim) outQim[j] = Q2i[j] * s;
    }

    const float4* qr4 = reinterpret_cast<const float4*>(Q2r + (size_t)bf * 36);
    const float4* qi4 = reinterpret_cast<const float4*>(Q2i + (size_t)bf * 36);
    float Qr[36], Qi[36];
#pragma unroll
    for (int e = 0; e < 9; e++) {
        const float4 a = qr4[e];
        Qr[4*e] = a.x; Qr[4*e+1] = a.y; Qr[4*e+2] = a.z; Qr[4*e+3] = a.w;
        const float4 c = qi4[e];
        Qi[4*e] = c.x; Qi[4*e+1] = c.y; Qi[4*e+2] = c.z; Qi[4*e+3] = c.w;
    }
    const float inv_scale = (float)FMTQ / s2;

    const int i = threadIdx.x;
    if (i < T4Q) {
        const float4* xr4 = reinterpret_cast<const float4*>(xre + (size_t)bf * MQ * TQ);
        const float4* xi4 = reinterpret_cast<const float4*>(xim + (size_t)bf * MQ * TQ);
        float ar[6][4], ai[6][4];
#pragma unroll
        for (int n = 0; n < 6; n++) {
            const float4 a = xr4[n * T4Q + i];
            ar[n][0] = a.x; ar[n][1] = a.y; ar[n][2] = a.z; ar[n][3] = a.w;
            const float4 c = xi4[n * T4Q + i];
            ai[n][0] = c.x; ai[n][1] = c.y; ai[n][2] = c.z; ai[n][3] = c.w;
        }
        float4* op4 = reinterpret_cast<float4*>(out + (size_t)bf * MQ * TQ);
#pragma unroll
        for (int m = 0; m < 6; m++) {
            float res[4];
#pragma unroll
            for (int e = 0; e < 4; e++) {
                float cr = 0.0f, ci = 0.0f;
#pragma unroll
                for (int n = 0; n < 6; n++) {
                    const float wr = Qr[m * 6 + n], wi = Qi[m * 6 + n];
                    cr += wr * ar[n][e] - wi * ai[n][e];
                    ci += wr * ai[n][e] + wi * ar[n][e];
                }
                res[e] = (cr * cr + ci * ci) * inv_scale;
            }
            op4[m * T4Q + i] = make_float4(res[0], res[1], res[2], res[3]);
        }
    }
}

// ---------------------------------------------------------------------------
extern "C" void kernel_launch(void* const* d_in, const int* in_sizes, int n_in,
                              void* d_out, int out_size, void* d_ws, size_t ws_size,
                              hipStream_t stream)
{
    (void)in_sizes; (void)n_in; (void)ws_size;
    const float* r   = (const float*)d_in[0];
    const float* Qre = (const float*)d_in[1];
    const float* Qim = (const float*)d_in[2];
    const float* xre = (const float*)d_in[3];
    const float* xim = (const float*)d_in[4];

    // workspace layout (floats): V | C | Q1r | Q1i | Q2r | Q2i | S1[16] | S2[16]
    float* ws  = (float*)d_ws;
    float* V   = ws;                          // BFQ*432
    float* Cw  = V   + (size_t)BFQ * 432;     // BFQ*72
    float* Q1r = Cw  + (size_t)BFQ * 72;      // BFQ*36
    float* Q1i = Q1r + (size_t)BFQ * 36;
    float* Q2r = Q1i + (size_t)BFQ * 36;
    float* Q2i = Q2r + (size_t)BFQ * 36;
    float* S1  = Q2i + (size_t)BFQ * 36;      // 16
    float* S2  = S1 + 16;                     // 16

    // Output layout (PLANAR, verified R2): [Q_re plane | Q_im plane | xt]
    const long long xt_elems = (long long)BFQ * MQ * TQ;        // 24,672,000
    const long long q_elems  = (long long)out_size - xt_elems;  // 296,064 or 148,032
    float* out_qre = (float*)d_out;
    float* out_qim = (q_elems >= 2LL * BFQ * 36) ? out_qre + (size_t)BFQ * 36 : nullptr;
    float* out_xt  = out_qre + (size_t)(q_elems > 0 ? q_elems : 2LL * BFQ * 36);

    k_zero<<<1, 64, 0, stream>>>(S1);   // zeros S1|S2 (32 contiguous floats)
    k_stats<<<BFQ, 256, 0, stream>>>(r, xre, xim, V, Cw, Qre, Qim, Q1r, Q1i, S1);
    const int iterGrid = (BFQ * 8 + 255) / 256;
    k_iter<<<iterGrid, 256, 0, stream>>>(V, Cw, Q1r, Q1i, S1, Q2r, Q2i, S2);
    k_xt<<<BFQ, 256, 0, stream>>>(xre, xim, Q2r, Q2i, S2, out_xt, out_qre, out_qim);
}